// Round 9
// baseline (79.098 us; speedup 1.0000x reference)
//
#include <hip/hip_runtime.h>
#include <stdint.h>

#define HH 4096
#define WW 4096
#define CC 3
#define NLOOP 1000
#define NCOPY 8192   // dedicated copy blocks in dispatch 1
#define NTHR 256
#define N4 ((CC * HH * WW) / 4)
#define CSTRIDE (NCOPY * NTHR)
static_assert(N4 == 6 * CSTRIDE, "copy loop must be exactly 6 iterations");

typedef float vfloat4 __attribute__((ext_vector_type(4)));

// Compact per-window record produced by dispatch 1, consumed by dispatch 2.
struct Rec {
  int psh, psw;
  unsigned long long live;
  float vals[CC][64];   // final values for live (c,q) slots
};
static_assert(sizeof(Rec) == 784, "rec size");

// JAX threefry2x32 (20 rounds), exact port of _threefry2x32_lowering.
__device__ __forceinline__ void tf2x32(uint32_t k0, uint32_t k1,
                                       uint32_t x0, uint32_t x1,
                                       uint32_t& o0, uint32_t& o1) {
  const uint32_t ks2 = k0 ^ k1 ^ 0x1BD11BDAu;
  x0 += k0; x1 += k1;
#define ROTL_(v,r) (((v)<<(r))|((v)>>(32-(r))))
#define RND_(r) { x0 += x1; x1 = ROTL_(x1,(r)); x1 ^= x0; }
  RND_(13) RND_(15) RND_(26) RND_(6)
  x0 += k1; x1 += ks2 + 1u;
  RND_(17) RND_(29) RND_(16) RND_(24)
  x0 += ks2; x1 += k0 + 2u;
  RND_(13) RND_(15) RND_(26) RND_(6)
  x0 += k0; x1 += k1 + 3u;
  RND_(17) RND_(29) RND_(16) RND_(24)
  x0 += k1; x1 += ks2 + 4u;
  RND_(13) RND_(15) RND_(26) RND_(6)
  x0 += ks2; x1 += k0 + 5u;
  o0 = x0; o1 = x1;
#undef RND_
#undef ROTL_
}

// 32-bit random_bits under partitionable threefry: XOR of the two output words.
__device__ __forceinline__ uint32_t rb32(uint32_t k0, uint32_t k1,
                                         uint32_t x0, uint32_t x1) {
  uint32_t o0, o1;
  tf2x32(k0, k1, x0, x1, o0, o1);
  return o0 ^ o1;
}

// Window geometry of loop iteration j: (ph, pw, wsh, wsw).
__device__ __forceinline__ void geom(uint32_t K1, int j,
                                     int& ph, int& pw, int& wsh, int& wsw) {
  uint32_t k0, k1, a0, a1;
  tf2x32(0u, K1, 0u, (uint32_t)j, k0, k1);
  uint32_t kh0,kh1,kw0,kw1,kp0,kp1,kq0,kq1;
  tf2x32(k0,k1,0u,0u,kh0,kh1);   // kh
  tf2x32(k0,k1,0u,1u,kw0,kw1);   // kw
  tf2x32(k0,k1,0u,2u,kp0,kp1);   // kph
  tf2x32(k0,k1,0u,3u,kq0,kq1);   // kpw
  tf2x32(kh0,kh1,0u,1u,a0,a1);   // randint internal split -> k2
  wsh = 1 + (int)(rb32(a0,a1,0u,0u) & 7u);
  tf2x32(kw0,kw1,0u,1u,a0,a1);
  wsw = 1 + (int)(rb32(a0,a1,0u,0u) & 7u);
  const float uh = __uint_as_float(0x3F800000u | (rb32(kp0,kp1,0u,0u) >> 9)) - 1.0f;
  const float uw = __uint_as_float(0x3F800000u | (rb32(kq0,kq1,0u,0u) >> 9)) - 1.0f;
  ph = (int)(uh * (float)(HH - wsh + 1));
  pw = (int)(uw * (float)(WW - wsw + 1));
}

// Dispatch 1. Blocks [0,NLOOP): full per-window pipeline (geometry, perm,
// live-mask via in-block recompute of LATER windows' geometry, value gather).
// Blocks [NLOOP, NLOOP+NCOPY): stream copy img->out (plain loads: L3 retains
// the input across replays; NT stores: output is write-once).
__global__ __launch_bounds__(NTHR) void k_main(
    const int* __restrict__ seedp, Rec* __restrict__ rec,
    const float* __restrict__ in, float* __restrict__ out) {
  const int b = blockIdx.x;
  const int tid = threadIdx.x;
  if (b >= NLOOP) {
    // ---- copy path: exactly 6 strided float4s per thread ----
    const vfloat4* __restrict__ in4 = (const vfloat4*)in;
    vfloat4* __restrict__ out4 = (vfloat4*)out;
    int idx = (b - NLOOP) * NTHR + tid;
    #pragma unroll
    for (int k = 0; k < 6; ++k) {
      const int i = idx + k * CSTRIDE;
      vfloat4 v = in4[i];
      __builtin_nontemporal_store(v, &out4[i]);
    }
    return;
  }

  // ---- window path ----
  const int i = b;
  const uint32_t K1 = (uint32_t)seedp[0];

  __shared__ uint32_t rb[CC * 64];
  __shared__ unsigned char mlist[64];
  __shared__ unsigned char srcbuf[CC][64];
  __shared__ unsigned long long shred[NTHR];

  // own geometry (uniform across threads; cheap)
  int ph, pw, wsh, wsw;
  geom(K1, i, ph, pw, wsh, wsw);
  const int psh = min(ph, HH - 8);
  const int psw = min(pw, WW - 8);
  const int offh = ph - psh, offw = pw - psw;
  const uint32_t colm = ((1u << wsw) - 1u) << offw;
  unsigned long long rows = (wsh == 8) ? ~0ull : ((1ull << (8 * wsh)) - 1ull);
  rows <<= (8 * offh);
  const unsigned long long mask =
      rows & (0x0101010101010101ull * (unsigned long long)colm);

  // permutation randoms: kperm = split(keys[i],5)[4]; 192 draws
  {
    uint32_t k0, k1, kr0, kr1;
    tf2x32(0u, K1, 0u, (uint32_t)i, k0, k1);
    tf2x32(k0, k1, 0u, 4u, kr0, kr1);
    if (tid < CC * 64) rb[tid] = rb32(kr0, kr1, 0u, (uint32_t)tid) >> 9;
  }

  // live mask: clear bits covered by LATER windows (geometry recomputed)
  unsigned long long clr = 0ull;
  for (int j = i + 1 + tid; j < NLOOP; j += NTHR) {
    int phj, pwj, whj, wwj;
    geom(K1, j, phj, pwj, whj, wwj);
    const int r0 = max(0, phj - psh), r1 = min(8, phj + whj - psh);
    const int c0 = max(0, pwj - psw), c1 = min(8, pwj + wwj - psw);
    if (r0 < r1 && c0 < c1) {
      const uint32_t cm = ((1u << (c1 - c0)) - 1u) << c0;
      const int nr = r1 - r0;
      unsigned long long rr = (nr == 8) ? ~0ull : ((1ull << (8 * nr)) - 1ull);
      rr <<= (8 * r0);
      clr |= rr & (0x0101010101010101ull * (unsigned long long)cm);
    }
  }
  shred[tid] = clr;

  if (tid < 64) {
    srcbuf[0][tid] = (unsigned char)tid;
    srcbuf[1][tid] = (unsigned char)tid;
    srcbuf[2][tid] = (unsigned char)tid;
    const int ordinal =
        __popcll(mask & ((tid == 0) ? 0ull : ((1ull << tid) - 1ull)));
    if ((mask >> tid) & 1ull) mlist[ordinal] = (unsigned char)tid;
  }
  __syncthreads();   // rb, mlist, identity srcbuf, shred ready

  // reduction of clear mask
  for (int s = NTHR / 2; s > 0; s >>= 1) {
    if (tid < s) shred[tid] |= shred[tid + s];
    __syncthreads();
  }
  const unsigned long long live = mask & ~shred[0];

  // stable argsort rank -> permutation (dest mlist[rank] <- src q)
  if (tid < CC * 64) {
    const int c = tid >> 6, q = tid & 63;
    if ((mask >> q) & 1ull) {
      const uint32_t myk = rb[(c << 6) | q];
      int rank = 0;
      for (int q2 = 0; q2 < 64; ++q2) {
        if ((mask >> q2) & 1ull) {
          const uint32_t k2 = rb[(c << 6) | q2];
          if (k2 < myk || (k2 == myk && q2 < q)) ++rank;
        }
      }
      srcbuf[c][mlist[rank]] = (unsigned char)q;
    }
  }
  __syncthreads();

  // gather final values for live slots; write compact record
  if (tid < CC * 64) {
    const int c = tid >> 6, q = tid & 63;
    float v = 0.0f;
    if ((live >> q) & 1ull) {
      const int s = srcbuf[c][q];
      const size_t base = (size_t)c * (size_t)HH * (size_t)WW;
      v = in[base + (size_t)(psh + (s >> 3)) * WW + (size_t)(psw + (s & 7))];
    }
    rec[i].vals[c][q] = v;
  }
  if (tid == 0) {
    rec[i].psh = psh; rec[i].psw = psw; rec[i].live = live;
  }
}

// Dispatch 2: trivial scatter of precomputed values.
__global__ __launch_bounds__(192) void k_scatter(
    const Rec* __restrict__ rec, float* __restrict__ out) {
  const int i = blockIdx.x;
  const int t = threadIdx.x;         // 192
  const int c = t >> 6, q = t & 63;
  const unsigned long long live = rec[i].live;
  if ((live >> q) & 1ull) {
    const int psh = rec[i].psh, psw = rec[i].psw;
    const size_t base = (size_t)c * (size_t)HH * (size_t)WW;
    out[base + (size_t)(psh + (q >> 3)) * WW + (size_t)(psw + (q & 7))] =
        rec[i].vals[c][q];
  }
}

extern "C" void kernel_launch(void* const* d_in, const int* in_sizes, int n_in,
                              void* d_out, int out_size, void* d_ws, size_t ws_size,
                              hipStream_t stream) {
  const float* img = (const float*)d_in[0];
  const int* seed = (const int*)d_in[1];
  float* out = (float*)d_out;
  Rec* rec = (Rec*)d_ws;   // needs NLOOP*784 = 784 KB

  hipLaunchKernelGGL(k_main, dim3(NLOOP + NCOPY), dim3(NTHR), 0, stream,
                     seed, rec, img, out);
  hipLaunchKernelGGL(k_scatter, dim3(NLOOP), dim3(192), 0, stream, rec, out);
}

// Round 10
// 76.186 us; speedup vs baseline: 1.0382x; 1.0382x over previous
//
#include <hip/hip_runtime.h>
#include <stdint.h>

#define HH 4096
#define WW 4096
#define CC 3
#define NLOOP 1000
#define NCOPY 8192   // copy blocks (scheduled FIRST)
#define NTHR 256
#define N4 ((CC * HH * WW) / 4)
#define CSTRIDE (NCOPY * NTHR)
static_assert(N4 == 6 * CSTRIDE, "copy loop must be exactly 6 iterations");

typedef float vfloat4 __attribute__((ext_vector_type(4)));

struct Desc {
  int psh, psw;
  unsigned long long mask;
  unsigned char src[CC][64];
  unsigned char pad[48];
};
static_assert(sizeof(Desc) == 256, "desc size");

// JAX threefry2x32 (20 rounds), exact port of _threefry2x32_lowering.
__device__ __forceinline__ void tf2x32(uint32_t k0, uint32_t k1,
                                       uint32_t x0, uint32_t x1,
                                       uint32_t& o0, uint32_t& o1) {
  const uint32_t ks2 = k0 ^ k1 ^ 0x1BD11BDAu;
  x0 += k0; x1 += k1;
#define ROTL_(v,r) (((v)<<(r))|((v)>>(32-(r))))
#define RND_(r) { x0 += x1; x1 = ROTL_(x1,(r)); x1 ^= x0; }
  RND_(13) RND_(15) RND_(26) RND_(6)
  x0 += k1; x1 += ks2 + 1u;
  RND_(17) RND_(29) RND_(16) RND_(24)
  x0 += ks2; x1 += k0 + 2u;
  RND_(13) RND_(15) RND_(26) RND_(6)
  x0 += k0; x1 += k1 + 3u;
  RND_(17) RND_(29) RND_(16) RND_(24)
  x0 += k1; x1 += ks2 + 4u;
  RND_(13) RND_(15) RND_(26) RND_(6)
  x0 += ks2; x1 += k0 + 5u;
  o0 = x0; o1 = x1;
#undef RND_
#undef ROTL_
}

// 32-bit random_bits under partitionable threefry: XOR of the two output words.
__device__ __forceinline__ uint32_t rb32(uint32_t k0, uint32_t k1,
                                         uint32_t x0, uint32_t x1) {
  uint32_t o0, o1;
  tf2x32(k0, k1, x0, x1, o0, o1);
  return o0 ^ o1;
}

// Dispatch 1. Blocks [0,NCOPY): stream copy img->out (plain loads: L3 keeps
// the input warm across replays; NT stores: write-once output, don't pollute).
// Blocks [NCOPY, NCOPY+NLOOP): per-window descriptor (geometry + permutation).
__global__ __launch_bounds__(NTHR) void k_copy_desc(
    const int* __restrict__ seedp, Desc* __restrict__ d, int4* __restrict__ geo,
    const float* __restrict__ in, float* __restrict__ out) {
  const int b = blockIdx.x;
  const int tid = threadIdx.x;
  if (b < NCOPY) {
    // ---- copy path: exactly 6 strided float4s per thread ----
    const vfloat4* __restrict__ in4 = (const vfloat4*)in;
    vfloat4* __restrict__ out4 = (vfloat4*)out;
    const int idx = b * NTHR + tid;
    #pragma unroll
    for (int k = 0; k < 6; ++k) {
      const int i = idx + k * CSTRIDE;
      vfloat4 v = in4[i];
      __builtin_nontemporal_store(v, &out4[i]);
    }
    return;
  }

  // ---- desc path ----
  const int i = b - NCOPY;
  const uint32_t K1 = (uint32_t)seedp[0];

  __shared__ uint32_t rb[CC * 64];
  __shared__ unsigned char mlist[64];
  __shared__ unsigned char srcbuf[CC][64];

  uint32_t k0, k1, a0, a1;
  tf2x32(0u, K1, 0u, (uint32_t)i, k0, k1);

  uint32_t kh0,kh1,kw0,kw1,kp0,kp1,kq0,kq1,kr0,kr1;
  tf2x32(k0,k1,0u,0u,kh0,kh1);   // kh
  tf2x32(k0,k1,0u,1u,kw0,kw1);   // kw
  tf2x32(k0,k1,0u,2u,kp0,kp1);   // kph
  tf2x32(k0,k1,0u,3u,kq0,kq1);   // kpw
  tf2x32(k0,k1,0u,4u,kr0,kr1);   // kperm

  // 192 uniform draws for kperm, one per thread 0..191
  if (tid < CC * 64) rb[tid] = rb32(kr0, kr1, 0u, (uint32_t)tid) >> 9;

  tf2x32(kh0,kh1,0u,1u,a0,a1);   // randint internal split -> k2
  const int wsh = 1 + (int)(rb32(a0,a1,0u,0u) & 7u);
  tf2x32(kw0,kw1,0u,1u,a0,a1);
  const int wsw = 1 + (int)(rb32(a0,a1,0u,0u) & 7u);

  const float uh = __uint_as_float(0x3F800000u | (rb32(kp0,kp1,0u,0u) >> 9)) - 1.0f;
  const float uw = __uint_as_float(0x3F800000u | (rb32(kq0,kq1,0u,0u) >> 9)) - 1.0f;

  const int ph = (int)(uh * (float)(HH - wsh + 1));
  const int pw = (int)(uw * (float)(WW - wsw + 1));
  const int psh = min(ph, HH - 8);
  const int psw = min(pw, WW - 8);
  const int offh = ph - psh;
  const int offw = pw - psw;

  const uint32_t colm = ((1u << wsw) - 1u) << offw;
  unsigned long long rows = (wsh == 8) ? ~0ull : ((1ull << (8 * wsh)) - 1ull);
  rows <<= (8 * offh);
  const unsigned long long mask =
      rows & (0x0101010101010101ull * (unsigned long long)colm);

  if (tid < 64) {
    srcbuf[0][tid] = (unsigned char)tid;
    srcbuf[1][tid] = (unsigned char)tid;
    srcbuf[2][tid] = (unsigned char)tid;
    const int ordinal =
        __popcll(mask & ((tid == 0) ? 0ull : ((1ull << tid) - 1ull)));
    if ((mask >> tid) & 1ull) mlist[ordinal] = (unsigned char)tid;
  }
  if (tid == 0) geo[i] = make_int4(ph, pw, wsh, wsw);
  __syncthreads();   // rb, mlist, identity srcbuf ready

  // stable argsort rank -> permutation (dest mlist[rank] <- src q)
  if (tid < CC * 64) {
    const int c = tid >> 6, q = tid & 63;
    if ((mask >> q) & 1ull) {
      const uint32_t myk = rb[(c << 6) | q];
      int rank = 0;
      for (int q2 = 0; q2 < 64; ++q2) {
        if ((mask >> q2) & 1ull) {
          const uint32_t k2 = rb[(c << 6) | q2];
          if (k2 < myk || (k2 == myk && q2 < q)) ++rank;
        }
      }
      srcbuf[c][mlist[rank]] = (unsigned char)q;
    }
  }
  __syncthreads();

  if (tid < CC * 64) {
    const int c = tid >> 6, q = tid & 63;
    d[i].src[c][q] = srcbuf[c][q];
  }
  if (tid == 0) {
    d[i].psh = psh; d[i].psw = psw; d[i].mask = mask;
  }
}

// Dispatch 2: live_i = mask_i minus coverage by later windows (dense 16B
// geometry reads, L2-hot), then scatter window i from the ORIGINAL image.
__global__ __launch_bounds__(NTHR) void k_live_apply(
    const float* __restrict__ in, float* __restrict__ out,
    const Desc* __restrict__ d, const int4* __restrict__ geo) {
  const int i = blockIdx.x;
  const int t = threadIdx.x;   // 256
  const int psh = d[i].psh, psw = d[i].psw;
  unsigned long long clr = 0ull;
  for (int j = i + 1 + t; j < NLOOP; j += NTHR) {
    const int4 g = geo[j];          // {ph, pw, wsh, wsw}
    const int r0 = max(0, g.x - psh), r1 = min(8, g.x + g.z - psh);
    const int c0 = max(0, g.y - psw), c1 = min(8, g.y + g.w - psw);
    if (r0 < r1 && c0 < c1) {
      const uint32_t cm = ((1u << (c1 - c0)) - 1u) << c0;
      const int nr = r1 - r0;
      unsigned long long rr = (nr == 8) ? ~0ull : ((1ull << (8 * nr)) - 1ull);
      rr <<= (8 * r0);
      clr |= rr & (0x0101010101010101ull * (unsigned long long)cm);
    }
  }
  __shared__ unsigned long long sh[NTHR];
  sh[t] = clr;
  __syncthreads();
  for (int s = NTHR / 2; s > 0; s >>= 1) {
    if (t < s) sh[t] |= sh[t + s];
    __syncthreads();
  }
  const unsigned long long live = d[i].mask & ~sh[0];

  // scatter: one thread per (c, q); sources always from the ORIGINAL image
  if (t < CC * 64) {
    const int c = t >> 6, q = t & 63;
    if ((live >> q) & 1ull) {
      const int s = d[i].src[c][q];
      const size_t base = (size_t)c * (size_t)HH * (size_t)WW;
      out[base + (size_t)(psh + (q >> 3)) * WW + (size_t)(psw + (q & 7))] =
          in[base + (size_t)(psh + (s >> 3)) * WW + (size_t)(psw + (s & 7))];
    }
  }
}

extern "C" void kernel_launch(void* const* d_in, const int* in_sizes, int n_in,
                              void* d_out, int out_size, void* d_ws, size_t ws_size,
                              hipStream_t stream) {
  const float* img = (const float*)d_in[0];
  const int* seed = (const int*)d_in[1];
  float* out = (float*)d_out;
  Desc* d = (Desc*)d_ws;                       // 256,000 B
  int4* geo = (int4*)((char*)d_ws + NLOOP * sizeof(Desc));   // +16,000 B

  hipLaunchKernelGGL(k_copy_desc, dim3(NCOPY + NLOOP), dim3(NTHR), 0, stream,
                     seed, d, geo, img, out);
  hipLaunchKernelGGL(k_live_apply, dim3(NLOOP), dim3(NTHR), 0, stream,
                     img, out, d, geo);
}

// Round 11
// 70.720 us; speedup vs baseline: 1.1185x; 1.0773x over previous
//
#include <hip/hip_runtime.h>
#include <stdint.h>

#define HH 4096
#define WW 4096
#define CC 3
#define NLOOP 1000
#define NCOPY 8192
#define NTHR 256
#define N4 ((CC * HH * WW) / 4)
#define CSTRIDE (NCOPY * NTHR)
static_assert(N4 == 6 * CSTRIDE, "copy loop must be exactly 6 iterations");

typedef float vfloat4 __attribute__((ext_vector_type(4)));

struct Desc {
  int psh, psw;
  unsigned long long mask;
  unsigned char src[CC][64];
  unsigned char pad[48];
};
static_assert(sizeof(Desc) == 256, "desc size");

// JAX threefry2x32 (20 rounds), exact port of _threefry2x32_lowering.
__device__ __forceinline__ void tf2x32(uint32_t k0, uint32_t k1,
                                       uint32_t x0, uint32_t x1,
                                       uint32_t& o0, uint32_t& o1) {
  const uint32_t ks2 = k0 ^ k1 ^ 0x1BD11BDAu;
  x0 += k0; x1 += k1;
#define ROTL_(v,r) (((v)<<(r))|((v)>>(32-(r))))
#define RND_(r) { x0 += x1; x1 = ROTL_(x1,(r)); x1 ^= x0; }
  RND_(13) RND_(15) RND_(26) RND_(6)
  x0 += k1; x1 += ks2 + 1u;
  RND_(17) RND_(29) RND_(16) RND_(24)
  x0 += ks2; x1 += k0 + 2u;
  RND_(13) RND_(15) RND_(26) RND_(6)
  x0 += k0; x1 += k1 + 3u;
  RND_(17) RND_(29) RND_(16) RND_(24)
  x0 += k1; x1 += ks2 + 4u;
  RND_(13) RND_(15) RND_(26) RND_(6)
  x0 += ks2; x1 += k0 + 5u;
  o0 = x0; o1 = x1;
#undef RND_
#undef ROTL_
}

// 32-bit random_bits under partitionable threefry: XOR of the two output words.
__device__ __forceinline__ uint32_t rb32(uint32_t k0, uint32_t k1,
                                         uint32_t x0, uint32_t x1) {
  uint32_t o0, o1;
  tf2x32(k0, k1, x0, x1, o0, o1);
  return o0 ^ o1;
}

// Dispatch 1. Blocks [0,NLOOP): per-window descriptor (VALU-bound, scheduled
// FIRST so it hides under the copy stream). Blocks [NLOOP,NLOOP+NCOPY):
// stream copy img->out (plain loads: L3 keeps input warm across replays;
// NT stores: write-once output, don't pollute caches).
__global__ __launch_bounds__(NTHR) void k_desc_copy(
    const int* __restrict__ seedp, Desc* __restrict__ d, int4* __restrict__ geo,
    const float* __restrict__ in, float* __restrict__ out) {
  const int b = blockIdx.x;
  const int tid = threadIdx.x;
  if (b >= NLOOP) {
    // ---- copy path: exactly 6 strided float4s per thread ----
    const vfloat4* __restrict__ in4 = (const vfloat4*)in;
    vfloat4* __restrict__ out4 = (vfloat4*)out;
    const int idx = (b - NLOOP) * NTHR + tid;
    #pragma unroll
    for (int k = 0; k < 6; ++k) {
      const int i = idx + k * CSTRIDE;
      vfloat4 v = in4[i];
      __builtin_nontemporal_store(v, &out4[i]);
    }
    return;
  }

  // ---- desc path ----
  const int i = b;
  const uint32_t K1 = (uint32_t)seedp[0];

  __shared__ uint32_t rb[CC * 64];
  __shared__ unsigned char mlist[64];
  __shared__ unsigned char srcbuf[CC][64];

  uint32_t k0, k1, a0, a1;
  tf2x32(0u, K1, 0u, (uint32_t)i, k0, k1);

  uint32_t kh0,kh1,kw0,kw1,kp0,kp1,kq0,kq1,kr0,kr1;
  tf2x32(k0,k1,0u,0u,kh0,kh1);   // kh
  tf2x32(k0,k1,0u,1u,kw0,kw1);   // kw
  tf2x32(k0,k1,0u,2u,kp0,kp1);   // kph
  tf2x32(k0,k1,0u,3u,kq0,kq1);   // kpw
  tf2x32(k0,k1,0u,4u,kr0,kr1);   // kperm

  // 192 uniform draws for kperm, one per thread 0..191
  if (tid < CC * 64) rb[tid] = rb32(kr0, kr1, 0u, (uint32_t)tid) >> 9;

  tf2x32(kh0,kh1,0u,1u,a0,a1);   // randint internal split -> k2
  const int wsh = 1 + (int)(rb32(a0,a1,0u,0u) & 7u);
  tf2x32(kw0,kw1,0u,1u,a0,a1);
  const int wsw = 1 + (int)(rb32(a0,a1,0u,0u) & 7u);

  const float uh = __uint_as_float(0x3F800000u | (rb32(kp0,kp1,0u,0u) >> 9)) - 1.0f;
  const float uw = __uint_as_float(0x3F800000u | (rb32(kq0,kq1,0u,0u) >> 9)) - 1.0f;

  const int ph = (int)(uh * (float)(HH - wsh + 1));
  const int pw = (int)(uw * (float)(WW - wsw + 1));
  const int psh = min(ph, HH - 8);
  const int psw = min(pw, WW - 8);
  const int offh = ph - psh;
  const int offw = pw - psw;

  const uint32_t colm = ((1u << wsw) - 1u) << offw;
  unsigned long long rows = (wsh == 8) ? ~0ull : ((1ull << (8 * wsh)) - 1ull);
  rows <<= (8 * offh);
  const unsigned long long mask =
      rows & (0x0101010101010101ull * (unsigned long long)colm);

  if (tid < 64) {
    srcbuf[0][tid] = (unsigned char)tid;
    srcbuf[1][tid] = (unsigned char)tid;
    srcbuf[2][tid] = (unsigned char)tid;
    const int ordinal =
        __popcll(mask & ((tid == 0) ? 0ull : ((1ull << tid) - 1ull)));
    if ((mask >> tid) & 1ull) mlist[ordinal] = (unsigned char)tid;
  }
  if (tid == 0) geo[i] = make_int4(ph, pw, wsh, wsw);
  __syncthreads();   // rb, mlist, identity srcbuf ready

  // stable argsort rank -> permutation (dest mlist[rank] <- src q)
  if (tid < CC * 64) {
    const int c = tid >> 6, q = tid & 63;
    if ((mask >> q) & 1ull) {
      const uint32_t myk = rb[(c << 6) | q];
      int rank = 0;
      for (int q2 = 0; q2 < 64; ++q2) {
        if ((mask >> q2) & 1ull) {
          const uint32_t k2 = rb[(c << 6) | q2];
          if (k2 < myk || (k2 == myk && q2 < q)) ++rank;
        }
      }
      srcbuf[c][mlist[rank]] = (unsigned char)q;
    }
  }
  __syncthreads();

  if (tid < CC * 64) {
    const int c = tid >> 6, q = tid & 63;
    d[i].src[c][q] = srcbuf[c][q];
  }
  if (tid == 0) {
    d[i].psh = psh; d[i].psw = psw; d[i].mask = mask;
  }
}

// Dispatch 2: live_i = mask_i minus coverage by later windows (dense 16B
// geometry reads, L2-hot), then scatter window i from the ORIGINAL image.
__global__ __launch_bounds__(NTHR) void k_live_apply(
    const float* __restrict__ in, float* __restrict__ out,
    const Desc* __restrict__ d, const int4* __restrict__ geo) {
  const int i = blockIdx.x;
  const int t = threadIdx.x;   // 256
  const int psh = d[i].psh, psw = d[i].psw;
  unsigned long long clr = 0ull;
  for (int j = i + 1 + t; j < NLOOP; j += NTHR) {
    const int4 g = geo[j];          // {ph, pw, wsh, wsw}
    const int r0 = max(0, g.x - psh), r1 = min(8, g.x + g.z - psh);
    const int c0 = max(0, g.y - psw), c1 = min(8, g.y + g.w - psw);
    if (r0 < r1 && c0 < c1) {
      const uint32_t cm = ((1u << (c1 - c0)) - 1u) << c0;
      const int nr = r1 - r0;
      unsigned long long rr = (nr == 8) ? ~0ull : ((1ull << (8 * nr)) - 1ull);
      rr <<= (8 * r0);
      clr |= rr & (0x0101010101010101ull * (unsigned long long)cm);
    }
  }
  // wave-level OR-reduce (no barriers), then one barrier for 4 wave results
  #pragma unroll
  for (int m = 32; m > 0; m >>= 1) clr |= __shfl_xor(clr, m, 64);
  __shared__ unsigned long long sh[4];
  if ((t & 63) == 0) sh[t >> 6] = clr;
  __syncthreads();
  const unsigned long long live =
      d[i].mask & ~(sh[0] | sh[1] | sh[2] | sh[3]);

  // scatter: one thread per (c, q); sources always from the ORIGINAL image
  if (t < CC * 64) {
    const int c = t >> 6, q = t & 63;
    if ((live >> q) & 1ull) {
      const int s = d[i].src[c][q];
      const size_t base = (size_t)c * (size_t)HH * (size_t)WW;
      out[base + (size_t)(psh + (q >> 3)) * WW + (size_t)(psw + (q & 7))] =
          in[base + (size_t)(psh + (s >> 3)) * WW + (size_t)(psw + (s & 7))];
    }
  }
}

extern "C" void kernel_launch(void* const* d_in, const int* in_sizes, int n_in,
                              void* d_out, int out_size, void* d_ws, size_t ws_size,
                              hipStream_t stream) {
  const float* img = (const float*)d_in[0];
  const int* seed = (const int*)d_in[1];
  float* out = (float*)d_out;
  Desc* d = (Desc*)d_ws;                                     // 256,000 B
  int4* geo = (int4*)((char*)d_ws + NLOOP * sizeof(Desc));   // +16,000 B

  hipLaunchKernelGGL(k_desc_copy, dim3(NLOOP + NCOPY), dim3(NTHR), 0, stream,
                     seed, d, geo, img, out);
  hipLaunchKernelGGL(k_live_apply, dim3(NLOOP), dim3(NTHR), 0, stream,
                     img, out, d, geo);
}